// Round 1
// 334.246 us; speedup vs baseline: 1.0402x; 1.0402x over previous
//
#include <hip/hip_runtime.h>

// MultiheadAttention: B=4, S=2048, D_MODEL=1024, H=16, D_K=64, fp32 in/out.
// Pipeline (all bf16 MFMA 16x16x32, fp32 accum):
//   1. transpose4: W[K][N] f32 -> Wt[N][K] bf16 (all 4 weights, one launch)
//   2. convert3: q/k/v f32 -> bf16 in one dispatch (scratch: d_out holds q,k; Cv holds v)
//   3. gemm_qkv: Q,K,V projections in ONE dispatch. NEW: 256x128 tile, 8 waves,
//      3-buffer LDS deep pipeline with counted s_waitcnt vmcnt(6) (never drained
//      in steady state), 4 sub-phases/K-tile with setprio(1) around MFMA clusters,
//      T2 bank-conflict fix via pre-swizzled GLD source + XOR'd ds_read,
//      bijective XCD swizzle (768 blocks = 3 clean rounds).
//   4. attn: unchanged (256-q blocks, un-normalized exp2 softmax, P in registers).
//   5. gemm_out: same new GEMM core, 256 blocks = exactly 1 CU round.

#define DM 1024
#define SQL 2048

typedef __attribute__((ext_vector_type(4))) float floatx4;
typedef __attribute__((ext_vector_type(8))) __bf16 bf16x8;
typedef __attribute__((ext_vector_type(4))) unsigned int uintx4;

// swizzled LDS address (halves): 64-half rows, 8-half chunks, chunk XOR row&7
#define SW(row, chunk) (((row) << 6) + ((((chunk) ^ ((row) & 7))) << 3))

// async 16B global->LDS copy; lds base must be wave-uniform (lane writes base+lane*16B)
#define GLD(gaddr, laddr)                                                              \
  __builtin_amdgcn_global_load_lds(                                                    \
      (const __attribute__((address_space(1))) unsigned int*)(gaddr),                  \
      (__attribute__((address_space(3))) unsigned int*)(laddr), 16, 0, 0)

__device__ __forceinline__ unsigned short f2bf(float f) {
  unsigned int u = __float_as_uint(f);
  u += 0x7fffu + ((u >> 16) & 1u);   // RNE
  return (unsigned short)(u >> 16);
}

// pack two f32 -> bf16 pair via v_perm (round-half-up)
__device__ __forceinline__ unsigned int pack_bf(float lo, float hi) {
  unsigned int a = __float_as_uint(lo) + 0x8000u;
  unsigned int b = __float_as_uint(hi) + 0x8000u;
  return __builtin_amdgcn_perm(b, a, 0x07060302u);  // {b.hi16, a.hi16}
}

// ---------------- all-4 weight transpose: W[1024][1024] f32 -> Wt[1024][1024] bf16
__global__ __launch_bounds__(256) void transpose4_kernel(
    const float* __restrict__ w0, const float* __restrict__ w1,
    const float* __restrict__ w2, const float* __restrict__ w3,
    unsigned short* __restrict__ t0, unsigned short* __restrict__ t1,
    unsigned short* __restrict__ t2, unsigned short* __restrict__ t3) {
  __shared__ unsigned short t[64][65];
  int z = blockIdx.z;
  const float* W = (z == 0) ? w0 : (z == 1) ? w1 : (z == 2) ? w2 : w3;
  unsigned short* Wt = (z == 0) ? t0 : (z == 1) ? t1 : (z == 2) ? t2 : t3;
  int tid = threadIdx.x;
  int n0 = blockIdx.x * 64, k0 = blockIdx.y * 64;
  for (int u = 0; u < 16; u++) {
    int idx = u * 256 + tid;
    int k = idx >> 6, n = idx & 63;
    t[k][n] = f2bf(W[(size_t)(k0 + k) * DM + n0 + n]);
  }
  __syncthreads();
  for (int u = 0; u < 16; u++) {
    int idx = u * 256 + tid;
    int n = idx >> 6, k = idx & 63;
    Wt[(size_t)(n0 + n) * DM + k0 + k] = t[k][n];
  }
}

// ---------------- f32 -> bf16 convert, 3 x 8M elements in one dispatch
__global__ __launch_bounds__(256) void convert3_kernel(
    const float* __restrict__ s0, const float* __restrict__ s1,
    const float* __restrict__ s2, unsigned short* __restrict__ d0,
    unsigned short* __restrict__ d1, unsigned short* __restrict__ d2) {
  int z = blockIdx.y;
  const float* S = (z == 0) ? s0 : (z == 1) ? s1 : s2;
  unsigned short* D = (z == 0) ? d0 : (z == 1) ? d1 : d2;
  int t = blockIdx.x * 256 + threadIdx.x;
  for (int u = 0; u < 8; u++) {
    int i = (u << 18) + t;
    float4 vv = ((const float4*)S)[i];
    uint2 p;
    p.x = pack_bf(vv.x, vv.y);
    p.y = pack_bf(vv.z, vv.w);
    ((uint2*)D)[i] = p;
  }
}

// ---------------- deep-pipelined GEMM core: C[256 x 128] tile, K=1024, BK=64.
// 8 waves as 4M x 2N (64x64 per wave). 3 LDS buffers; staging for K-tile t+2 is
// issued during K-tile t into buffer (t+2)%3 -> never touches the active buffer
// (race-free by construction). K-tile boundary: s_waitcnt vmcnt(6) + s_barrier
// (6 = one K-tile of loads/thread in flight; counted, never drained mid-loop).
// 4 sub-phases per K-tile: {ds_read frags || issue 2 GLD -> barrier ->
// setprio(1) 8xMFMA setprio(0) -> barrier}.
// Bank conflicts: GLD dest must be linear, so the global SOURCE is pre-swizzled
// (lane loads chunk l8^r8) and ds_read XORs chunk with row&7 (same involution).
__device__ __forceinline__ void gemm_core_256x128(
    const unsigned short* __restrict__ A, const unsigned short* __restrict__ Bt,
    int m0, int n0, unsigned short* lds_a, unsigned short* lds_b,
    floatx4 acc[4][4]) {
  int tid = threadIdx.x;
  int wave = tid >> 6, lane = tid & 63;
  int quad = lane >> 4, c16 = lane & 15;
  int wm = wave >> 1, wn = wave & 1;
  int r8 = lane >> 3, l8 = lane & 7;
  int xch = (l8 ^ r8) << 3;  // pre-swizzled source chunk offset (halves)

  int r7 = c16 & 7;
  // per-lane ds_read base offsets (halves) for ks=0 / ks=1; +i*1024 per M/N frag
  int aoff0 = ((wm * 64 + c16) << 6) + ((quad ^ r7) << 3);
  int aoff1 = ((wm * 64 + c16) << 6) + (((4 + quad) ^ r7) << 3);
  int boff0 = ((wn * 64 + c16) << 6) + ((quad ^ r7) << 3);
  int boff1 = ((wn * 64 + c16) << 6) + (((4 + quad) ^ r7) << 3);

  int aq = wave * 4;  // A staged as 32 row-groups of 8 rows, 4 per wave
  int bq = wave * 2;  // B staged as 16 row-groups of 8 rows, 2 per wave

#define STG_A(bufp, kt, u) \
  GLD(&A[(size_t)(m0 + (aq + (u)) * 8 + r8) * DM + (kt) + xch], (bufp) + (aq + (u)) * 512)
#define STG_B(bufp, kt, u) \
  GLD(&Bt[(size_t)(n0 + (bq + (u)) * 8 + r8) * DM + (kt) + xch], (bufp) + (bq + (u)) * 512)

  const floatx4 fz = {0.f, 0.f, 0.f, 0.f};
#pragma unroll
  for (int i = 0; i < 4; i++)
#pragma unroll
    for (int j = 0; j < 4; j++) acc[i][j] = fz;

  // prologue: stage K-tiles 0 and 1 (12 loads/thread total)
#pragma unroll
  for (int u = 0; u < 4; u++) STG_A(lds_a, 0, u);
  STG_B(lds_b, 0, 0);
  STG_B(lds_b, 0, 1);
#pragma unroll
  for (int u = 0; u < 4; u++) STG_A(lds_a + 16384, 64, u);
  STG_B(lds_b + 8192, 64, 0);
  STG_B(lds_b + 8192, 64, 1);

  int cur = 0;
#pragma unroll 1
  for (int t = 0; t < 16; ++t) {
    // K-tile boundary: own K-tile landed, next K-tile's 6 loads stay in flight.
    if (t < 15) asm volatile("s_waitcnt vmcnt(6)\n\ts_barrier" ::: "memory");
    else        asm volatile("s_waitcnt vmcnt(0)\n\ts_barrier" ::: "memory");

    const unsigned short* la = lds_a + cur * 16384;
    const unsigned short* lb = lds_b + cur * 8192;
    int stg = cur + 2;
    if (stg >= 3) stg -= 3;
    unsigned short* sa = lds_a + stg * 16384;
    unsigned short* sb = lds_b + stg * 8192;
    bool do_st = (t < 14);
    int kt2 = (t + 2) << 6;

    bf16x8 a_[2], b0[4], b1[4];

    // ---- phase 0: ks=0, i=0..1 (+ all B ks=0); stage A u0,u1
    a_[0] = *(const bf16x8*)&la[aoff0];
    a_[1] = *(const bf16x8*)&la[aoff0 + 1024];
    b0[0] = *(const bf16x8*)&lb[boff0];
    b0[1] = *(const bf16x8*)&lb[boff0 + 1024];
    b0[2] = *(const bf16x8*)&lb[boff0 + 2048];
    b0[3] = *(const bf16x8*)&lb[boff0 + 3072];
    if (do_st) { STG_A(sa, kt2, 0); STG_A(sa, kt2, 1); }
    __builtin_amdgcn_s_barrier();
    __builtin_amdgcn_s_setprio(1);
#pragma unroll
    for (int j = 0; j < 4; j++)
      acc[0][j] = __builtin_amdgcn_mfma_f32_16x16x32_bf16(a_[0], b0[j], acc[0][j], 0, 0, 0);
#pragma unroll
    for (int j = 0; j < 4; j++)
      acc[1][j] = __builtin_amdgcn_mfma_f32_16x16x32_bf16(a_[1], b0[j], acc[1][j], 0, 0, 0);
    __builtin_amdgcn_s_setprio(0);
    __builtin_amdgcn_s_barrier();

    // ---- phase 1: ks=0, i=2..3; stage A u2,u3
    a_[0] = *(const bf16x8*)&la[aoff0 + 2048];
    a_[1] = *(const bf16x8*)&la[aoff0 + 3072];
    if (do_st) { STG_A(sa, kt2, 2); STG_A(sa, kt2, 3); }
    __builtin_amdgcn_s_barrier();
    __builtin_amdgcn_s_setprio(1);
#pragma unroll
    for (int j = 0; j < 4; j++)
      acc[2][j] = __builtin_amdgcn_mfma_f32_16x16x32_bf16(a_[0], b0[j], acc[2][j], 0, 0, 0);
#pragma unroll
    for (int j = 0; j < 4; j++)
      acc[3][j] = __builtin_amdgcn_mfma_f32_16x16x32_bf16(a_[1], b0[j], acc[3][j], 0, 0, 0);
    __builtin_amdgcn_s_setprio(0);
    __builtin_amdgcn_s_barrier();

    // ---- phase 2: ks=1, i=0..1 (+ all B ks=1); stage B u0,u1
    a_[0] = *(const bf16x8*)&la[aoff1];
    a_[1] = *(const bf16x8*)&la[aoff1 + 1024];
    b1[0] = *(const bf16x8*)&lb[boff1];
    b1[1] = *(const bf16x8*)&lb[boff1 + 1024];
    b1[2] = *(const bf16x8*)&lb[boff1 + 2048];
    b1[3] = *(const bf16x8*)&lb[boff1 + 3072];
    if (do_st) { STG_B(sb, kt2, 0); STG_B(sb, kt2, 1); }
    __builtin_amdgcn_s_barrier();
    __builtin_amdgcn_s_setprio(1);
#pragma unroll
    for (int j = 0; j < 4; j++)
      acc[0][j] = __builtin_amdgcn_mfma_f32_16x16x32_bf16(a_[0], b1[j], acc[0][j], 0, 0, 0);
#pragma unroll
    for (int j = 0; j < 4; j++)
      acc[1][j] = __builtin_amdgcn_mfma_f32_16x16x32_bf16(a_[1], b1[j], acc[1][j], 0, 0, 0);
    __builtin_amdgcn_s_setprio(0);
    __builtin_amdgcn_s_barrier();

    // ---- phase 3: ks=1, i=2..3
    a_[0] = *(const bf16x8*)&la[aoff1 + 2048];
    a_[1] = *(const bf16x8*)&la[aoff1 + 3072];
    __builtin_amdgcn_s_barrier();
    __builtin_amdgcn_s_setprio(1);
#pragma unroll
    for (int j = 0; j < 4; j++)
      acc[2][j] = __builtin_amdgcn_mfma_f32_16x16x32_bf16(a_[0], b1[j], acc[2][j], 0, 0, 0);
#pragma unroll
    for (int j = 0; j < 4; j++)
      acc[3][j] = __builtin_amdgcn_mfma_f32_16x16x32_bf16(a_[1], b1[j], acc[3][j], 0, 0, 0);
    __builtin_amdgcn_s_setprio(0);
    // boundary sync of next iteration provides the trailing barrier

    cur = cur + 1;
    if (cur >= 3) cur = 0;
  }
#undef STG_A
#undef STG_B
}

// ---------------- batched QKV projection GEMM: 768 blocks (3 clean CU rounds)
// z=0: Qb = (Aq@wqt + bq)*qscale  (bf16 row-major)
// z=1: Kb =  Ak@wkt + bk          (bf16 row-major)
// z=2: Vt =  Av@wvt + bv          (bf16 [b,h,d,s] kv-bit-permuted)
__global__ __launch_bounds__(512, 2) void gemm_qkv_kernel(
    const unsigned short* __restrict__ Aq, const unsigned short* __restrict__ Ak,
    const unsigned short* __restrict__ Av, const unsigned short* __restrict__ wqt,
    const unsigned short* __restrict__ wkt, const unsigned short* __restrict__ wvt,
    const float* __restrict__ bq, const float* __restrict__ bk,
    const float* __restrict__ bv, unsigned short* __restrict__ Qb,
    unsigned short* __restrict__ Kb, unsigned short* __restrict__ VtOut,
    float qscale) {
  __shared__ unsigned short lds_a[3 * 256 * 64];  // 96 KiB
  __shared__ unsigned short lds_b[3 * 128 * 64];  // 48 KiB

  // bijective XCD swizzle: 768 blocks, 96 consecutive logical tiles per XCD
  int lin = blockIdx.x + (blockIdx.y << 3) + (blockIdx.z << 8);
  int swz = (lin & 7) * 96 + (lin >> 3);
  int z = swz >> 8, rem = swz & 255;
  int m0 = (rem >> 3) << 8;  // mTile*256
  int n0 = (rem & 7) << 7;   // nTile*128

  const unsigned short* A  = (z == 0) ? Aq : (z == 1) ? Ak : Av;
  const unsigned short* Bt = (z == 0) ? wqt : (z == 1) ? wkt : wvt;
  const float* bias = (z == 0) ? bq : (z == 1) ? bk : bv;

  floatx4 acc[4][4];
  gemm_core_256x128(A, Bt, m0, n0, lds_a, lds_b, acc);

  int tid = threadIdx.x;
  int wave = tid >> 6, lane = tid & 63;
  int quad = lane >> 4, c16 = lane & 15;
  int wm = wave >> 1, wn = wave & 1;

  float scale = (z == 0) ? qscale : 1.0f;
#pragma unroll
  for (int i = 0; i < 4; i++)
#pragma unroll
    for (int j = 0; j < 4; j++) {
      int gc = n0 + wn * 64 + j * 16 + c16;
      float bvv = bias[gc];
      float val[4];
#pragma unroll
      for (int r = 0; r < 4; r++) val[r] = (acc[i][j][r] + bvv) * scale;
      int gr0 = m0 + wm * 64 + i * 16 + quad * 4;
      if (z < 2) {
        unsigned short* O = (z == 0) ? Qb : Kb;
#pragma unroll
        for (int r = 0; r < 4; r++) O[(size_t)(gr0 + r) * DM + gc] = f2bf(val[r]);
      } else {
        // V transposed + kv-permuted: s stored at column c = (s5, s3, s2, s4, s1, s0)
        int hh = gc >> 6, dd = gc & 63;
        int bidx = gr0 >> 11, srow = gr0 & 2047;
        int s6 = srow & 63;   // low 2 bits 0
        int c6 = (s6 & 32) | ((s6 & 8) << 1) | ((s6 & 4) << 1) | ((s6 & 16) >> 2) | (s6 & 3);
        int srowp = (srow & ~63) | c6;
        uint2 pk;
        pk.x = pack_bf(val[0], val[1]);
        pk.y = pack_bf(val[2], val[3]);
        *(uint2*)&VtOut[((size_t)(bidx * 16 + hh) * 64 + dd) * SQL + srowp] = pk;
      }
    }
}

// ---------------- output GEMM: out[8192][1024] f32 = Cv_bf16 @ wot^T + bo
// 256 blocks = exactly one block per CU (single round).
__global__ __launch_bounds__(512, 2) void gemm_out_kernel(
    const unsigned short* __restrict__ A, const unsigned short* __restrict__ Bt,
    const float* __restrict__ bias, float* __restrict__ O) {
  __shared__ unsigned short lds_a[3 * 256 * 64];
  __shared__ unsigned short lds_b[3 * 128 * 64];

  int lin = blockIdx.x + (blockIdx.y << 3);
  int swz = (lin & 7) * 32 + (lin >> 3);
  int m0 = (swz >> 3) << 8;
  int n0 = (swz & 7) << 7;

  floatx4 acc[4][4];
  gemm_core_256x128(A, Bt, m0, n0, lds_a, lds_b, acc);

  int tid = threadIdx.x;
  int wave = tid >> 6, lane = tid & 63;
  int quad = lane >> 4, c16 = lane & 15;
  int wm = wave >> 1, wn = wave & 1;

#pragma unroll
  for (int i = 0; i < 4; i++)
#pragma unroll
    for (int j = 0; j < 4; j++) {
      int gc = n0 + wn * 64 + j * 16 + c16;
      float bvv = bias[gc];
      int gr0 = m0 + wm * 64 + i * 16 + quad * 4;
#pragma unroll
      for (int r = 0; r < 4; r++) O[(size_t)(gr0 + r) * DM + gc] = acc[i][j][r] + bvv;
    }
}

// ---------------- flash attention, S^T formulation, un-normalized softmax.
// (unchanged from previous round)
__global__ __launch_bounds__(256, 2) void attn_kernel(
    const unsigned short* __restrict__ Qb, const unsigned short* __restrict__ Kb,
    const unsigned short* __restrict__ Vt, unsigned short* __restrict__ Cv) {
  __shared__ unsigned short lds_k[2][64 * 64];   // [kv][d] swizzled
  __shared__ unsigned short lds_v[2][64 * 64];   // [d][kv-permuted] swizzled
  int tid = threadIdx.x;
  int wave = tid >> 6, lane = tid & 63;
  int quad = lane >> 4, c16 = lane & 15;
  int bh = blockIdx.x, qt = blockIdx.y;
  int b = bh >> 4, h = bh & 15;

  int sr0 = tid >> 3, sc = tid & 7;              // rows sr0, sr0+32
  const unsigned short* kbase = &Kb[(size_t)(b * SQL) * DM + h * 64 + sc * 8];
  const unsigned short* vbase = &Vt[(size_t)(bh * 64) * SQL + sc * 8];

  bf16x8 qf[4][2];
  for (int i = 0; i < 4; i++)
    for (int ks = 0; ks < 2; ks++) {
      int gr = b * SQL + qt * 256 + wave * 64 + i * 16 + c16;
      qf[i][ks] = *(const bf16x8*)&Qb[(size_t)gr * DM + h * 64 + ks * 32 + quad * 8];
    }

  const floatx4 fzero = {0.f, 0.f, 0.f, 0.f};
  floatx4 acc[4][4];  // O^T: [dt][i]; d=16dt+4quad+r, q=qt*256+wave*64+16i+c16
  for (int dt = 0; dt < 4; dt++)
    for (int i = 0; i < 4; i++) acc[dt][i] = fzero;
  float l_[4] = {0.f, 0.f, 0.f, 0.f};

  for (int u = 0; u < 2; u++) {
    int r = sr0 + u * 32;
    *(uint4*)&lds_k[0][SW(r, sc)] = *(const uint4*)&kbase[(size_t)r * DM];
    *(uint4*)&lds_v[0][SW(r, sc)] = *(const uint4*)&vbase[(size_t)r * SQL];
  }
  __syncthreads();

  for (int t = 0; t < 32; t++) {
    int cur = t & 1;
    uint4 kreg[2], vreg[2];
    if (t + 1 < 32) {
      int t1 = (t + 1) * 64;
      for (int u = 0; u < 2; u++) {
        int r = sr0 + u * 32;
        kreg[u] = *(const uint4*)&kbase[(size_t)(t1 + r) * DM];
        vreg[u] = *(const uint4*)&vbase[(size_t)r * SQL + t1];
      }
    }

    floatx4 s[4][4];
    for (int i = 0; i < 4; i++)
      for (int jt = 0; jt < 4; jt++) s[i][jt] = fzero;
    for (int ks = 0; ks < 2; ks++) {
      bf16x8 kf[4];
      for (int jt = 0; jt < 4; jt++)
        kf[jt] = *(const bf16x8*)&lds_k[cur][SW(jt * 16 + c16, ks * 4 + quad)];
      for (int i = 0; i < 4; i++)
        for (int jt = 0; jt < 4; jt++)
          s[i][jt] = __builtin_amdgcn_mfma_f32_16x16x32_bf16(kf[jt], qf[i][ks], s[i][jt], 0, 0, 0);
    }

    uintx4 pw[4][2];  // [i][ks]
    for (int i = 0; i < 4; i++) {
      float sum = l_[i];
      for (int jt = 0; jt < 4; jt++)
        for (int r = 0; r < 4; r++) {
          float p = __builtin_amdgcn_exp2f(s[i][jt][r]);
          s[i][jt][r] = p;
          sum += p;
        }
      l_[i] = sum;
      for (int ks = 0; ks < 2; ks++) {
        pw[i][ks].x = pack_bf(s[i][2 * ks][0], s[i][2 * ks][1]);
        pw[i][ks].y = pack_bf(s[i][2 * ks][2], s[i][2 * ks][3]);
        pw[i][ks].z = pack_bf(s[i][2 * ks + 1][0], s[i][2 * ks + 1][1]);
        pw[i][ks].w = pack_bf(s[i][2 * ks + 1][2], s[i][2 * ks + 1][3]);
      }
    }

    for (int ks = 0; ks < 2; ks++) {
      for (int dt = 0; dt < 4; dt++) {
        bf16x8 av = *(const bf16x8*)&lds_v[cur][SW(dt * 16 + c16, ks * 4 + quad)];
        for (int i = 0; i < 4; i++)
          acc[dt][i] = __builtin_amdgcn_mfma_f32_16x16x32_bf16(
              av, __builtin_bit_cast(bf16x8, pw[i][ks]), acc[dt][i], 0, 0, 0);
      }
    }

    if (t + 1 < 32) {
      int nxt = cur ^ 1;
      for (int u = 0; u < 2; u++) {
        int r = sr0 + u * 32;
        *(uint4*)&lds_k[nxt][SW(r, sc)] = kreg[u];
        *(uint4*)&lds_v[nxt][SW(r, sc)] = vreg[u];
      }
    }
    __syncthreads();
  }

  for (int i = 0; i < 4; i++) {
    l_[i] += __shfl_xor(l_[i], 16);
    l_[i] += __shfl_xor(l_[i], 32);
    float inv = 1.f / l_[i];
    int gr = b * SQL + qt * 256 + wave * 64 + i * 16 + c16;
    for (int dt = 0; dt < 4; dt++) {
      uint2 pkw;
      pkw.x = pack_bf(acc[dt][i][0] * inv, acc[dt][i][1] * inv);
      pkw.y = pack_bf(acc[dt][i][2] * inv, acc[dt][i][3] * inv);
      *(uint2*)&Cv[(size_t)gr * DM + h * 64 + dt * 16 + quad * 4] = pkw;
    }
  }
}

extern "C" void kernel_launch(void* const* d_in, const int* in_sizes, int n_in,
                              void* d_out, int out_size, void* d_ws, size_t ws_size,
                              hipStream_t stream) {
  const float* q  = (const float*)d_in[0];
  const float* k  = (const float*)d_in[1];
  const float* v  = (const float*)d_in[2];
  const float* wq = (const float*)d_in[3];
  const float* bq = (const float*)d_in[4];
  const float* wk = (const float*)d_in[5];
  const float* bk = (const float*)d_in[6];
  const float* wv = (const float*)d_in[7];
  const float* bv = (const float*)d_in[8];
  const float* wo = (const float*)d_in[9];
  const float* bo = (const float*)d_in[10];
  float* out = (float*)d_out;

  char* ws = (char*)d_ws;
  unsigned short* wqt = (unsigned short*)(ws + (size_t)0);
  unsigned short* wkt = (unsigned short*)(ws + ((size_t)2 << 20));
  unsigned short* wvt = (unsigned short*)(ws + ((size_t)4 << 20));
  unsigned short* wot = (unsigned short*)(ws + ((size_t)6 << 20));
  unsigned short* Qb  = (unsigned short*)(ws + ((size_t)8 << 20));
  unsigned short* Kb  = (unsigned short*)(ws + ((size_t)24 << 20));
  unsigned short* Vt  = (unsigned short*)(ws + ((size_t)40 << 20));
  unsigned short* Cv  = (unsigned short*)(ws + ((size_t)56 << 20));
  // bf16-A scratch: d_out (32 MiB, rewritten by gemm_out at the end) holds q,k; Cv holds v.
  unsigned short* Aq = (unsigned short*)d_out;
  unsigned short* Ak = (unsigned short*)d_out + ((size_t)8 << 20);  // elements: 8Mi halves = 16 MiB
  unsigned short* Av = Cv;

  const float QSCALE = 0.125f * 1.44269504088896340736f;  // 1/sqrt(64) * log2(e)

  dim3 blk(256);
  transpose4_kernel<<<dim3(16, 16, 4), blk, 0, stream>>>(wq, wk, wv, wo, wqt, wkt, wvt, wot);
  convert3_kernel<<<dim3(1024, 3), blk, 0, stream>>>(q, k, v, Aq, Ak, Av);
  gemm_qkv_kernel<<<dim3(8, 32, 3), dim3(512), 0, stream>>>(Aq, Ak, Av, wqt, wkt, wvt,
                                                            bq, bk, bv, Qb, Kb, Vt, QSCALE);
  attn_kernel<<<dim3(64, 8), blk, 0, stream>>>(Qb, Kb, Vt, Cv);
  gemm_out_kernel<<<dim3(8, 32), dim3(512), 0, stream>>>(Cv, wot, bo, out);
}